// Round 9
// baseline (253.192 us; speedup 1.0000x reference)
//
#include <hip/hip_runtime.h>
#include <math.h>

#define NPIX 50176      // 16*56*56
#define CDIM 384
#define HEADS 6
#define NLOGIT 54       // HEADS*9
#define HH 56
#define WW 56

typedef __attribute__((ext_vector_type(8))) __bf16 bf16x8;
typedef __attribute__((ext_vector_type(4))) float f32x4;

__device__ __forceinline__ void glds16(const void* g, void* l) {
  __builtin_amdgcn_global_load_lds(
      (const __attribute__((address_space(1))) unsigned int*)g,
      (__attribute__((address_space(3))) unsigned int*)l, 16, 0, 0);
}

// ---------------------------------------------------------------------------
// One prep dispatch:
//  range 0: W_v   [K][N] -> Wtv bf16 [N][K];  W_proj -> Wtp likewise
//  range 1: W_attn[384][54] -> Wta bf16 [64][384] (zero rows 54..63)
//  range 2: b_attn -> bpad[64]
// ---------------------------------------------------------------------------
__global__ __launch_bounds__(256) void prep_kernel(
    const float* __restrict__ W_v, const float* __restrict__ W_proj,
    const float* __restrict__ W_attn, const float* __restrict__ b_attn,
    __bf16* __restrict__ Wtv, __bf16* __restrict__ Wtp,
    __bf16* __restrict__ Wta, float* __restrict__ bpad) {
  const int idx = blockIdx.x * 256 + threadIdx.x;
  const int WSZ = CDIM * CDIM;  // 147456
  if (idx < WSZ) {
    const int n = idx / CDIM, k = idx % CDIM;
    Wtv[idx] = (__bf16)W_v[k * CDIM + n];
    Wtp[idx] = (__bf16)W_proj[k * CDIM + n];
  } else if (idx < WSZ + 64 * CDIM) {
    const int r = idx - WSZ;
    const int n = r / CDIM, k = r % CDIM;
    Wta[r] = (__bf16)((n < NLOGIT) ? W_attn[k * NLOGIT + n] : 0.f);
  } else if (idx < WSZ + 64 * CDIM + 64) {
    const int n = idx - WSZ - 64 * CDIM;
    bpad[n] = (n < NLOGIT) ? b_attn[n] : 0.f;
  }
}

// ---------------------------------------------------------------------------
// Cast x fp32 -> bf16, 16 elements / thread. Pure streaming.
// ---------------------------------------------------------------------------
__global__ __launch_bounds__(256) void cast_x_kernel(
    const float* __restrict__ x, __bf16* __restrict__ xb) {
  const size_t i = (size_t)blockIdx.x * 256 + threadIdx.x;
  const float4* src = (const float4*)x + i * 4;
  const float4 f0 = src[0];
  const float4 f1 = src[1];
  const float4 f2 = src[2];
  const float4 f3 = src[3];
  bf16x8 o0, o1;
  o0[0] = (__bf16)f0.x; o0[1] = (__bf16)f0.y; o0[2] = (__bf16)f0.z; o0[3] = (__bf16)f0.w;
  o0[4] = (__bf16)f1.x; o0[5] = (__bf16)f1.y; o0[6] = (__bf16)f1.z; o0[7] = (__bf16)f1.w;
  o1[0] = (__bf16)f2.x; o1[1] = (__bf16)f2.y; o1[2] = (__bf16)f2.z; o1[3] = (__bf16)f2.w;
  o1[4] = (__bf16)f3.x; o1[5] = (__bf16)f3.y; o1[6] = (__bf16)f3.z; o1[7] = (__bf16)f3.w;
  ((bf16x8*)xb)[i * 2]     = o0;
  ((bf16x8*)xb)[i * 2 + 1] = o1;
}

// ---------------------------------------------------------------------------
// Merged dispatch: grid (NPIX/128, 4).
//   by<3 : v = bf16(xb @ Wtv^T + b_v), 128x128 tile.
//   by==3: logits = xb @ Wta^T + bpad (128x64), fused softmax -> attn.
// ---------------------------------------------------------------------------
__global__ __launch_bounds__(256) void gemm_v_logit_kernel(
    const __bf16* __restrict__ xb, const __bf16* __restrict__ Wtv,
    const float* __restrict__ b_v, __bf16* __restrict__ v,
    const __bf16* __restrict__ Wta, const float* __restrict__ bpad,
    float* __restrict__ attn) {
  __shared__ char smem[34816];
  __bf16 (*As)[32] = (__bf16(*)[32])smem;            // [128][32]
  __bf16 (*Bs)[32] = (__bf16(*)[32])(smem + 8192);   // [128][32]
  float (*Ls)[68]  = (float(*)[68])smem;             // [128][68] (logit epi)

  const int tid  = threadIdx.x;
  const int wave = tid >> 6;
  const int lane = tid & 63;
  const int bm   = blockIdx.x * 128;
  const int lrow  = lane >> 2;
  const int lkoff = (lane & 3) * 8;
  const int frow  = lane & 15;
  const int fk    = (lane >> 4) * 8;

  if (blockIdx.y < 3) {
    const int bn = blockIdx.y * 128;
    const int wr = (wave >> 1) * 64;
    const int wc = (wave & 1) * 64;
    f32x4 acc[4][4] = {};

    for (int k0 = 0; k0 < CDIM; k0 += 32) {
      const __bf16* ga = xb  + (size_t)(bm + wave * 32 + lrow) * CDIM + k0 + lkoff;
      const __bf16* gb = Wtv + (size_t)(bn + wave * 32 + lrow) * CDIM + k0 + lkoff;
      glds16(ga,                     &As[wave * 32][0]);
      glds16(ga + 16 * (size_t)CDIM, &As[wave * 32 + 16][0]);
      glds16(gb,                     &Bs[wave * 32][0]);
      glds16(gb + 16 * (size_t)CDIM, &Bs[wave * 32 + 16][0]);
      __syncthreads();

      bf16x8 a[4], b[4];
      #pragma unroll
      for (int mi = 0; mi < 4; ++mi)
        a[mi] = *(const bf16x8*)&As[wr + mi * 16 + frow][fk];
      #pragma unroll
      for (int ni = 0; ni < 4; ++ni)
        b[ni] = *(const bf16x8*)&Bs[wc + ni * 16 + frow][fk];
      #pragma unroll
      for (int mi = 0; mi < 4; ++mi)
        #pragma unroll
        for (int ni = 0; ni < 4; ++ni)
          acc[mi][ni] = __builtin_amdgcn_mfma_f32_16x16x32_bf16(
              a[mi], b[ni], acc[mi][ni], 0, 0, 0);
      __syncthreads();
    }

    const int orow = (lane >> 4) * 4;
    #pragma unroll
    for (int mi = 0; mi < 4; ++mi) {
      #pragma unroll
      for (int ni = 0; ni < 4; ++ni) {
        const int n = bn + wc + ni * 16 + frow;
        const float bvl = b_v[n];
        #pragma unroll
        for (int r = 0; r < 4; ++r) {
          const int m = bm + wr + mi * 16 + orow + r;
          v[(size_t)m * CDIM + n] = (__bf16)(acc[mi][ni][r] + bvl);
        }
      }
    }
  } else {
    f32x4 acc[2][4] = {};

    for (int k0 = 0; k0 < CDIM; k0 += 32) {
      const __bf16* ga = xb  + (size_t)(bm + wave * 32 + lrow) * CDIM + k0 + lkoff;
      const __bf16* gb = Wta + (size_t)(wave * 16 + lrow) * CDIM + k0 + lkoff;
      glds16(ga,                     &As[wave * 32][0]);
      glds16(ga + 16 * (size_t)CDIM, &As[wave * 32 + 16][0]);
      glds16(gb,                     &Bs[wave * 16][0]);
      __syncthreads();

      bf16x8 a[2], b[4];
      #pragma unroll
      for (int mi = 0; mi < 2; ++mi)
        a[mi] = *(const bf16x8*)&As[wave * 32 + mi * 16 + frow][fk];
      #pragma unroll
      for (int ni = 0; ni < 4; ++ni)
        b[ni] = *(const bf16x8*)&Bs[ni * 16 + frow][fk];
      #pragma unroll
      for (int mi = 0; mi < 2; ++mi)
        #pragma unroll
        for (int ni = 0; ni < 4; ++ni)
          acc[mi][ni] = __builtin_amdgcn_mfma_f32_16x16x32_bf16(
              a[mi], b[ni], acc[mi][ni], 0, 0, 0);
      __syncthreads();
    }

    float bvl[4];
    #pragma unroll
    for (int ni = 0; ni < 4; ++ni) bvl[ni] = bpad[ni * 16 + frow];
    const int orow = (lane >> 4) * 4;
    #pragma unroll
    for (int mi = 0; mi < 2; ++mi)
      #pragma unroll
      for (int ni = 0; ni < 4; ++ni)
        #pragma unroll
        for (int r = 0; r < 4; ++r)
          Ls[wave * 32 + mi * 16 + orow + r][ni * 16 + frow] =
              acc[mi][ni][r] + bvl[ni];
    __syncthreads();

    #pragma unroll
    for (int it = 0; it < 3; ++it) {
      const int task = it * 256 + tid;
      const int pl = task / HEADS;
      const int h  = task % HEADS;
      const float* row = &Ls[pl][h * 9];
      float m = row[0];
      #pragma unroll
      for (int w = 1; w < 9; ++w) m = fmaxf(m, row[w]);
      float e[9], s = 0.f;
      #pragma unroll
      for (int w = 0; w < 9; ++w) { e[w] = __expf(row[w] - m); s += e[w]; }
      const float inv = 1.f / s;
      float* op = &attn[(size_t)(bm + pl) * NLOGIT + h * 9];
      #pragma unroll
      for (int w = 0; w < 9; ++w) op[w] = e[w] * inv;
    }
  }
}

// ---------------------------------------------------------------------------
// Fused aggregate + proj GEMM: out[M][N] = y[M][K] @ Wtp[N][K]^T + b_proj,
// where y[p][k] = sum_w attn[p,head(k),w] * v[nbr(p,w),k] is computed
// on the fly into the A-tile (LDS) each K-step. 128x128 tile, BK=32.
// B-stage glds16 issued first (async), then VALU aggregation overlaps it.
// ---------------------------------------------------------------------------
__global__ __launch_bounds__(256) void gemm_proj_agg_kernel(
    const __bf16* __restrict__ v, const float* __restrict__ attn,
    const __bf16* __restrict__ Bt, const float* __restrict__ bias,
    float* __restrict__ Out) {
  __shared__ __bf16 As[128][32];
  __shared__ __bf16 Bs[128][32];

  const int tid  = threadIdx.x;
  const int wave = tid >> 6;
  const int lane = tid & 63;
  const int bm = blockIdx.x * 128;
  const int bn = blockIdx.y * 128;

  const int lrow  = lane >> 2;
  const int lkoff = (lane & 3) * 8;
  const int frow  = lane & 15;
  const int fk    = (lane >> 4) * 8;
  const int wr = (wave >> 1) * 64;
  const int wc = (wave & 1) * 64;

  // --- per-thread A-stage task decode (2 tasks: pixels px, px+64; same cg)
  const int px0 = tid >> 2;        // 0..63
  const int cg  = tid & 3;         // channel group *8 within K-step
  int ibase[2], jpos[2];           // image row/col per task
  size_t vbase[2];                 // &v[(bimg*HH+i)*WW+j] channel base
  #pragma unroll
  for (int t = 0; t < 2; ++t) {
    const int p = bm + px0 + t * 64;
    const int bimg = p / (HH * WW);
    const int rem  = p % (HH * WW);
    ibase[t] = rem / WW;
    jpos[t]  = rem % WW;
    vbase[t] = ((size_t)(bimg * HH + ibase[t]) * WW + jpos[t]) * CDIM;
  }

  float aw[2][9];
  f32x4 acc[4][4] = {};

  for (int ks = 0; ks < 12; ++ks) {
    const int k0 = ks * 32;
    // B-stage first (async global->LDS), overlaps the VALU aggregation below.
    const __bf16* gb = Bt + (size_t)(bn + wave * 32 + lrow) * CDIM + k0 + lkoff;
    glds16(gb,                     &Bs[wave * 32][0]);
    glds16(gb + 16 * (size_t)CDIM, &Bs[wave * 32 + 16][0]);

    // reload attn weights when the head changes (every 2 K-steps)
    if ((ks & 1) == 0) {
      const int head = k0 >> 6;
      #pragma unroll
      for (int t = 0; t < 2; ++t) {
        const int p = bm + px0 + t * 64;
        const float* ap = attn + (size_t)p * NLOGIT + head * 9;
        #pragma unroll
        for (int w = 0; w < 9; ++w) aw[t][w] = ap[w];
      }
    }

    // A-stage: aggregate y[p][k0+cg*8 .. +8] from v neighbors.
    #pragma unroll
    for (int t = 0; t < 2; ++t) {
      const int i = ibase[t], j = jpos[t];
      float a8[8] = {};
      #pragma unroll
      for (int ki = 0; ki < 3; ++ki) {
        const int ii = i + ki - 1;
        if (ii < 0 || ii >= HH) continue;
        #pragma unroll
        for (int kj = 0; kj < 3; ++kj) {
          const int jj = j + kj - 1;
          if (jj < 0 || jj >= WW) continue;
          const float wgt = aw[t][ki * 3 + kj];
          const bf16x8 vv = *(const bf16x8*)&v[
              vbase[t] + ((ii - i) * WW + (jj - j)) * CDIM + k0 + cg * 8];
          #pragma unroll
          for (int q = 0; q < 8; ++q) a8[q] += wgt * (float)vv[q];
        }
      }
      bf16x8 o;
      #pragma unroll
      for (int q = 0; q < 8; ++q) o[q] = (__bf16)a8[q];
      *(bf16x8*)&As[px0 + t * 64][cg * 8] = o;
    }
    __syncthreads();

    bf16x8 a[4], b[4];
    #pragma unroll
    for (int mi = 0; mi < 4; ++mi)
      a[mi] = *(const bf16x8*)&As[wr + mi * 16 + frow][fk];
    #pragma unroll
    for (int ni = 0; ni < 4; ++ni)
      b[ni] = *(const bf16x8*)&Bs[wc + ni * 16 + frow][fk];
    #pragma unroll
    for (int mi = 0; mi < 4; ++mi)
      #pragma unroll
      for (int ni = 0; ni < 4; ++ni)
        acc[mi][ni] = __builtin_amdgcn_mfma_f32_16x16x32_bf16(
            a[mi], b[ni], acc[mi][ni], 0, 0, 0);
    __syncthreads();
  }

  const int orow = (lane >> 4) * 4;
  #pragma unroll
  for (int mi = 0; mi < 4; ++mi) {
    #pragma unroll
    for (int ni = 0; ni < 4; ++ni) {
      const int n = bn + wc + ni * 16 + frow;
      const float bvl = bias[n];
      #pragma unroll
      for (int r = 0; r < 4; ++r) {
        const int m = bm + wr + mi * 16 + orow + r;
        Out[(size_t)m * CDIM + n] = acc[mi][ni][r] + bvl;
      }
    }
  }
}

// ---------------------------------------------------------------------------
extern "C" void kernel_launch(void* const* d_in, const int* in_sizes, int n_in,
                              void* d_out, int out_size, void* d_ws,
                              size_t ws_size, hipStream_t stream) {
  const float* x      = (const float*)d_in[0];
  const float* W_attn = (const float*)d_in[1];
  const float* b_attn = (const float*)d_in[2];
  const float* W_v    = (const float*)d_in[3];
  const float* b_v    = (const float*)d_in[4];
  const float* W_proj = (const float*)d_in[5];
  const float* b_proj = (const float*)d_in[6];
  float* out = (float*)d_out;

  char* w = (char*)d_ws;
  __bf16* xb   = (__bf16*)w;  w += (size_t)NPIX * CDIM * 2;   // 38.5MB
  __bf16* v    = (__bf16*)w;  w += (size_t)NPIX * CDIM * 2;   // 38.5MB
  float*  attn = (float*)w;   w += (size_t)NPIX * NLOGIT * 4; // 10.8MB
  __bf16* Wta  = (__bf16*)w;  w += 64 * CDIM * 2;             // 48KB
  float*  bpad = (float*)w;   w += 64 * 4;
  __bf16* Wtv  = (__bf16*)w;  w += CDIM * CDIM * 2;
  __bf16* Wtp  = (__bf16*)w;  w += CDIM * CDIM * 2;

  // prep (one dispatch)
  const int prep_n = CDIM * CDIM + 64 * CDIM + 64;
  prep_kernel<<<(prep_n + 255) / 256, 256, 0, stream>>>(
      W_v, W_proj, W_attn, b_attn, Wtv, Wtp, Wta, bpad);

  // 0. x -> bf16 (streaming)
  cast_x_kernel<<<(NPIX * CDIM / 16) / 256, 256, 0, stream>>>(x, xb);

  // 1. merged: v-GEMM + logits/softmax
  gemm_v_logit_kernel<<<dim3(NPIX / 128, 4), 256, 0, stream>>>(
      xb, Wtv, b_v, v, Wta, bpad, attn);

  // 2. fused aggregation + proj GEMM (fp32 out)
  gemm_proj_agg_kernel<<<dim3(NPIX / 128, CDIM / 128), 256, 0, stream>>>(
      v, attn, Wtp, b_proj, out);
}

// Round 10
// 126.618 us; speedup vs baseline: 1.9997x; 1.9997x over previous
//
#include <hip/hip_runtime.h>
#include <math.h>

#define NPIX 50176      // 16*56*56
#define CDIM 384
#define HEADS 6
#define NLOGIT 54       // HEADS*9
#define HH 56
#define WW 56

typedef __attribute__((ext_vector_type(8))) __bf16 bf16x8;
typedef __attribute__((ext_vector_type(4))) float f32x4;

__device__ __forceinline__ void glds16(const void* g, void* l) {
  __builtin_amdgcn_global_load_lds(
      (const __attribute__((address_space(1))) unsigned int*)g,
      (__attribute__((address_space(3))) unsigned int*)l, 16, 0, 0);
}

// ---------------------------------------------------------------------------
// One prep dispatch:
//  range 0: W_v   [K][N] -> Wtv bf16 [N][K];  W_proj -> Wtp likewise
//  range 1: W_attn[384][54] -> Wta bf16 [64][384] (zero rows 54..63)
//  range 2: b_attn -> bpad[64]
// ---------------------------------------------------------------------------
__global__ __launch_bounds__(256) void prep_kernel(
    const float* __restrict__ W_v, const float* __restrict__ W_proj,
    const float* __restrict__ W_attn, const float* __restrict__ b_attn,
    __bf16* __restrict__ Wtv, __bf16* __restrict__ Wtp,
    __bf16* __restrict__ Wta, float* __restrict__ bpad) {
  const int idx = blockIdx.x * 256 + threadIdx.x;
  const int WSZ = CDIM * CDIM;  // 147456
  if (idx < WSZ) {
    const int n = idx / CDIM, k = idx % CDIM;
    Wtv[idx] = (__bf16)W_v[k * CDIM + n];
    Wtp[idx] = (__bf16)W_proj[k * CDIM + n];
  } else if (idx < WSZ + 64 * CDIM) {
    const int r = idx - WSZ;
    const int n = r / CDIM, k = r % CDIM;
    Wta[r] = (__bf16)((n < NLOGIT) ? W_attn[k * NLOGIT + n] : 0.f);
  } else if (idx < WSZ + 64 * CDIM + 64) {
    const int n = idx - WSZ - 64 * CDIM;
    bpad[n] = (n < NLOGIT) ? b_attn[n] : 0.f;
  }
}

// ---------------------------------------------------------------------------
// Merged dispatch: grid (NPIX/128, 4). A-stage reads fp32 x directly and
// converts to bf16 in registers (kills the standalone cast_x pass + xb buf).
//   by<3 : v = bf16(x @ Wtv^T + b_v), 128x128 tile.
//   by==3: logits = x @ Wta^T + bpad (128x64), fused softmax -> attn.
// ---------------------------------------------------------------------------
__global__ __launch_bounds__(256) void gemm_v_logit_kernel(
    const float* __restrict__ X, const __bf16* __restrict__ Wtv,
    const float* __restrict__ b_v, __bf16* __restrict__ v,
    const __bf16* __restrict__ Wta, const float* __restrict__ bpad,
    float* __restrict__ attn) {
  __shared__ char smem[34816];
  __bf16 (*As)[32] = (__bf16(*)[32])smem;            // [128][32]
  __bf16 (*Bs)[32] = (__bf16(*)[32])(smem + 8192);   // [128][32]
  float (*Ls)[68]  = (float(*)[68])smem;             // [128][68] (logit epi)

  const int tid  = threadIdx.x;
  const int wave = tid >> 6;
  const int lane = tid & 63;
  const int bm   = blockIdx.x * 128;
  const int lrow  = lane >> 2;        // 0..15
  const int lkoff = (lane & 3) * 8;   // 0,8,16,24
  const int frow  = lane & 15;
  const int fk    = (lane >> 4) * 8;

  const bool is_logit = (blockIdx.y == 3);
  const int bn = is_logit ? 0 : blockIdx.y * 128;
  const int wr = (wave >> 1) * 64;
  const int wc = (wave & 1) * 64;

  f32x4 acc[4][4] = {};

  for (int k0 = 0; k0 < CDIM; k0 += 32) {
    // A-stage: fp32 x -> regs (issued first; latency hidden by TLP)
    const float* gx = X + (size_t)(bm + wave * 32 + lrow) * CDIM + k0 + lkoff;
    const float4 f0 = *(const float4*)(gx + 0);
    const float4 f1 = *(const float4*)(gx + 4);
    const float4 f2 = *(const float4*)(gx + 16 * CDIM + 0);
    const float4 f3 = *(const float4*)(gx + 16 * CDIM + 4);

    // B-stage: async global->LDS (flies while we convert)
    if (is_logit) {
      const __bf16* gb = Wta + (size_t)(wave * 16 + lrow) * CDIM + k0 + lkoff;
      glds16(gb, &Bs[wave * 16][0]);
    } else {
      const __bf16* gb = Wtv + (size_t)(bn + wave * 32 + lrow) * CDIM + k0 + lkoff;
      glds16(gb,                     &Bs[wave * 32][0]);
      glds16(gb + 16 * (size_t)CDIM, &Bs[wave * 32 + 16][0]);
    }

    bf16x8 h0, h1;
    h0[0] = (__bf16)f0.x; h0[1] = (__bf16)f0.y; h0[2] = (__bf16)f0.z; h0[3] = (__bf16)f0.w;
    h0[4] = (__bf16)f1.x; h0[5] = (__bf16)f1.y; h0[6] = (__bf16)f1.z; h0[7] = (__bf16)f1.w;
    h1[0] = (__bf16)f2.x; h1[1] = (__bf16)f2.y; h1[2] = (__bf16)f2.z; h1[3] = (__bf16)f2.w;
    h1[4] = (__bf16)f3.x; h1[5] = (__bf16)f3.y; h1[6] = (__bf16)f3.z; h1[7] = (__bf16)f3.w;
    *(bf16x8*)&As[wave * 32 + lrow][lkoff]      = h0;
    *(bf16x8*)&As[wave * 32 + 16 + lrow][lkoff] = h1;
    __syncthreads();

    if (is_logit) {
      bf16x8 a[2], b[4];
      #pragma unroll
      for (int mi = 0; mi < 2; ++mi)
        a[mi] = *(const bf16x8*)&As[wave * 32 + mi * 16 + frow][fk];
      #pragma unroll
      for (int ni = 0; ni < 4; ++ni)
        b[ni] = *(const bf16x8*)&Bs[ni * 16 + frow][fk];
      #pragma unroll
      for (int mi = 0; mi < 2; ++mi)
        #pragma unroll
        for (int ni = 0; ni < 4; ++ni)
          acc[mi][ni] = __builtin_amdgcn_mfma_f32_16x16x32_bf16(
              a[mi], b[ni], acc[mi][ni], 0, 0, 0);
    } else {
      bf16x8 a[4], b[4];
      #pragma unroll
      for (int mi = 0; mi < 4; ++mi)
        a[mi] = *(const bf16x8*)&As[wr + mi * 16 + frow][fk];
      #pragma unroll
      for (int ni = 0; ni < 4; ++ni)
        b[ni] = *(const bf16x8*)&Bs[wc + ni * 16 + frow][fk];
      #pragma unroll
      for (int mi = 0; mi < 4; ++mi)
        #pragma unroll
        for (int ni = 0; ni < 4; ++ni)
          acc[mi][ni] = __builtin_amdgcn_mfma_f32_16x16x32_bf16(
              a[mi], b[ni], acc[mi][ni], 0, 0, 0);
    }
    __syncthreads();
  }

  if (!is_logit) {
    const int orow = (lane >> 4) * 4;
    #pragma unroll
    for (int mi = 0; mi < 4; ++mi) {
      #pragma unroll
      for (int ni = 0; ni < 4; ++ni) {
        const int n = bn + wc + ni * 16 + frow;
        const float bvl = b_v[n];
        #pragma unroll
        for (int r = 0; r < 4; ++r) {
          const int m = bm + wr + mi * 16 + orow + r;
          v[(size_t)m * CDIM + n] = (__bf16)(acc[mi][ni][r] + bvl);
        }
      }
    }
  } else {
    float bvl[4];
    #pragma unroll
    for (int ni = 0; ni < 4; ++ni) bvl[ni] = bpad[ni * 16 + frow];
    const int orow = (lane >> 4) * 4;
    #pragma unroll
    for (int mi = 0; mi < 2; ++mi)
      #pragma unroll
      for (int ni = 0; ni < 4; ++ni)
        #pragma unroll
        for (int r = 0; r < 4; ++r)
          Ls[wave * 32 + mi * 16 + orow + r][ni * 16 + frow] =
              acc[mi][ni][r] + bvl[ni];
    __syncthreads();

    #pragma unroll
    for (int it = 0; it < 3; ++it) {
      const int task = it * 256 + tid;
      const int pl = task / HEADS;
      const int h  = task % HEADS;
      const float* row = &Ls[pl][h * 9];
      float m = row[0];
      #pragma unroll
      for (int w = 1; w < 9; ++w) m = fmaxf(m, row[w]);
      float e[9], s = 0.f;
      #pragma unroll
      for (int w = 0; w < 9; ++w) { e[w] = __expf(row[w] - m); s += e[w]; }
      const float inv = 1.f / s;
      float* op = &attn[(size_t)(bm + pl) * NLOGIT + h * 9];
      #pragma unroll
      for (int w = 0; w < 9; ++w) op[w] = e[w] * inv;
    }
  }
}

// ---------------------------------------------------------------------------
// bf16 MFMA GEMM (proj): Out[M][N] fp32 = A[M][K] @ Bt[N][K]^T + bias.
// ---------------------------------------------------------------------------
__global__ __launch_bounds__(256) void gemm_proj_kernel(
    const __bf16* __restrict__ A, const __bf16* __restrict__ Bt,
    const float* __restrict__ bias, float* __restrict__ Out) {
  __shared__ __bf16 As[128][32];
  __shared__ __bf16 Bs[128][32];

  const int tid  = threadIdx.x;
  const int wave = tid >> 6;
  const int lane = tid & 63;
  const int bm = blockIdx.x * 128;
  const int bn = blockIdx.y * 128;

  const int lrow  = lane >> 2;
  const int lkoff = (lane & 3) * 8;
  const int frow  = lane & 15;
  const int fk    = (lane >> 4) * 8;
  const int wr = (wave >> 1) * 64;
  const int wc = (wave & 1) * 64;

  f32x4 acc[4][4] = {};

  for (int k0 = 0; k0 < CDIM; k0 += 32) {
    const __bf16* ga = A  + (size_t)(bm + wave * 32 + lrow) * CDIM + k0 + lkoff;
    const __bf16* gb = Bt + (size_t)(bn + wave * 32 + lrow) * CDIM + k0 + lkoff;
    glds16(ga,                     &As[wave * 32][0]);
    glds16(ga + 16 * (size_t)CDIM, &As[wave * 32 + 16][0]);
    glds16(gb,                     &Bs[wave * 32][0]);
    glds16(gb + 16 * (size_t)CDIM, &Bs[wave * 32 + 16][0]);
    __syncthreads();

    bf16x8 a[4], b[4];
    #pragma unroll
    for (int mi = 0; mi < 4; ++mi)
      a[mi] = *(const bf16x8*)&As[wr + mi * 16 + frow][fk];
    #pragma unroll
    for (int ni = 0; ni < 4; ++ni)
      b[ni] = *(const bf16x8*)&Bs[wc + ni * 16 + frow][fk];
    #pragma unroll
    for (int mi = 0; mi < 4; ++mi)
      #pragma unroll
      for (int ni = 0; ni < 4; ++ni)
        acc[mi][ni] = __builtin_amdgcn_mfma_f32_16x16x32_bf16(
            a[mi], b[ni], acc[mi][ni], 0, 0, 0);
    __syncthreads();
  }

  const int orow = (lane >> 4) * 4;
  #pragma unroll
  for (int mi = 0; mi < 4; ++mi) {
    #pragma unroll
    for (int ni = 0; ni < 4; ++ni) {
      const int n = bn + wc + ni * 16 + frow;
      const float bvl = bias[n];
      #pragma unroll
      for (int r = 0; r < 4; ++r) {
        const int m = bm + wr + mi * 16 + orow + r;
        Out[(size_t)m * CDIM + n] = acc[mi][ni][r] + bvl;
      }
    }
  }
}

// ---------------------------------------------------------------------------
// Window aggregation, 4 vertically-adjacent pixels per thread (R8 version).
// ---------------------------------------------------------------------------
__global__ __launch_bounds__(256) void aggregate_kernel(
    const __bf16* __restrict__ v, const float* __restrict__ attn,
    __bf16* __restrict__ y) {
  const int idx = blockIdx.x * 256 + threadIdx.x;  // NPIX/4 * 48 = 602112
  const int cg = idx % 48;
  const int pg = idx / 48;
  const int c  = cg * 8;
  const int b  = pg / ((HH / 4) * WW);
  const int r2 = pg % ((HH / 4) * WW);
  const int i0 = (r2 / WW) * 4;
  const int j  = r2 % WW;
  const int head = c >> 6;

  const int pbase = (b * HH + i0) * WW + j;
  float aw[4][9];
  #pragma unroll
  for (int p = 0; p < 4; ++p) {
    const float* ap = attn + (size_t)(pbase + p * WW) * NLOGIT + head * 9;
    #pragma unroll
    for (int w = 0; w < 9; ++w) aw[p][w] = ap[w];
  }

  const bool j0ok = (j > 0), j2ok = (j < WW - 1);
  float acc[4][8] = {};

  #pragma unroll
  for (int li = 0; li < 6; ++li) {
    const int ii = i0 - 1 + li;
    if (ii < 0 || ii >= HH) continue;
    const __bf16* vrow = v + ((size_t)(b * HH + ii) * WW + j) * CDIM + c;
    float ch[3][8];
    #pragma unroll
    for (int kj = 0; kj < 3; ++kj) {
      const bool ok = (kj == 0) ? j0ok : (kj == 2) ? j2ok : true;
      if (ok) {
        const bf16x8 vv = *(const bf16x8*)(vrow + (kj - 1) * CDIM);
        #pragma unroll
        for (int q = 0; q < 8; ++q) ch[kj][q] = (float)vv[q];
      } else {
        #pragma unroll
        for (int q = 0; q < 8; ++q) ch[kj][q] = 0.f;
      }
    }
    #pragma unroll
    for (int p = 0; p < 4; ++p) {
      const int ki = li - p;
      if (ki < 0 || ki > 2) continue;
      #pragma unroll
      for (int kj = 0; kj < 3; ++kj) {
        const float w = aw[p][ki * 3 + kj];
        #pragma unroll
        for (int q = 0; q < 8; ++q) acc[p][q] += w * ch[kj][q];
      }
    }
  }

  #pragma unroll
  for (int p = 0; p < 4; ++p) {
    bf16x8 o;
    #pragma unroll
    for (int q = 0; q < 8; ++q) o[q] = (__bf16)acc[p][q];
    *(bf16x8*)&y[(size_t)(pbase + p * WW) * CDIM + c] = o;
  }
}

// ---------------------------------------------------------------------------
extern "C" void kernel_launch(void* const* d_in, const int* in_sizes, int n_in,
                              void* d_out, int out_size, void* d_ws,
                              size_t ws_size, hipStream_t stream) {
  const float* x      = (const float*)d_in[0];
  const float* W_attn = (const float*)d_in[1];
  const float* b_attn = (const float*)d_in[2];
  const float* W_v    = (const float*)d_in[3];
  const float* b_v    = (const float*)d_in[4];
  const float* W_proj = (const float*)d_in[5];
  const float* b_proj = (const float*)d_in[6];
  float* out = (float*)d_out;

  char* w = (char*)d_ws;
  __bf16* v    = (__bf16*)w;  w += (size_t)NPIX * CDIM * 2;   // 38.5MB
  __bf16* y    = (__bf16*)w;  w += (size_t)NPIX * CDIM * 2;   // 38.5MB
  float*  attn = (float*)w;   w += (size_t)NPIX * NLOGIT * 4; // 10.8MB
  __bf16* Wta  = (__bf16*)w;  w += 64 * CDIM * 2;             // 48KB
  float*  bpad = (float*)w;   w += 64 * 4;
  __bf16* Wtv  = (__bf16*)w;  w += CDIM * CDIM * 2;
  __bf16* Wtp  = (__bf16*)w;  w += CDIM * CDIM * 2;

  // prep (one dispatch)
  const int prep_n = CDIM * CDIM + 64 * CDIM + 64;
  prep_kernel<<<(prep_n + 255) / 256, 256, 0, stream>>>(
      W_v, W_proj, W_attn, b_attn, Wtv, Wtp, Wta, bpad);

  // 1. merged: v-GEMM + logits/softmax (reads fp32 x, converts in-kernel)
  gemm_v_logit_kernel<<<dim3(NPIX / 128, 4), 256, 0, stream>>>(
      x, Wtv, b_v, v, Wta, bpad, attn);

  // 2. window aggregation -> y (bf16), 4 px/thread
  aggregate_kernel<<<(NPIX / 4 * 48) / 256, 256, 0, stream>>>(v, attn, y);

  // 3. out = y @ W_proj + b_proj (fp32 out)
  gemm_proj_kernel<<<dim3(NPIX / 128, CDIM / 128), 256, 0, stream>>>(
      y, Wtp, b_proj, out);
}

// Round 11
// 119.399 us; speedup vs baseline: 2.1206x; 1.0605x over previous
//
#include <hip/hip_runtime.h>
#include <math.h>

#define NPIX 50176      // 16*56*56
#define CDIM 384
#define HEADS 6
#define NLOGIT 54       // HEADS*9
#define HH 56
#define WW 56
#define NCAT 448        // 384 v-cols + 64 padded logit cols

typedef __attribute__((ext_vector_type(8))) __bf16 bf16x8;
typedef __attribute__((ext_vector_type(4))) float f32x4;

__device__ __forceinline__ void glds16(const void* g, void* l) {
  __builtin_amdgcn_global_load_lds(
      (const __attribute__((address_space(1))) unsigned int*)g,
      (__attribute__((address_space(3))) unsigned int*)l, 16, 0, 0);
}

// ---------------------------------------------------------------------------
// One prep dispatch:
//  idx < 448*384          : Wcat[n][k] = n<384 ? W_v[k][n] : (n-384<54 ?
//                            W_attn[k][n-384] : 0)   (bf16)
//  next 384*384           : Wtp[n][k] = W_proj[k][n] (bf16)
//  next 64                : bpad[n] = n<54 ? b_attn[n] : 0
// ---------------------------------------------------------------------------
__global__ __launch_bounds__(256) void prep_kernel(
    const float* __restrict__ W_v, const float* __restrict__ W_proj,
    const float* __restrict__ W_attn, const float* __restrict__ b_attn,
    __bf16* __restrict__ Wcat, __bf16* __restrict__ Wtp,
    float* __restrict__ bpad) {
  const int idx = blockIdx.x * 256 + threadIdx.x;
  const int CATSZ = NCAT * CDIM;   // 172032
  const int WSZ   = CDIM * CDIM;   // 147456
  if (idx < CATSZ) {
    const int n = idx / CDIM, k = idx % CDIM;
    float val;
    if (n < CDIM) val = W_v[k * CDIM + n];
    else {
      const int nn = n - CDIM;
      val = (nn < NLOGIT) ? W_attn[k * NLOGIT + nn] : 0.f;
    }
    Wcat[idx] = (__bf16)val;
  } else if (idx < CATSZ + WSZ) {
    const int r = idx - CATSZ;
    const int n = r / CDIM, k = r % CDIM;
    Wtp[r] = (__bf16)W_proj[k * CDIM + n];
  } else if (idx < CATSZ + WSZ + 64) {
    const int n = idx - CATSZ - WSZ;
    bpad[n] = (n < NLOGIT) ? b_attn[n] : 0.f;
  }
}

// ---------------------------------------------------------------------------
// Merged full-N GEMM: BM=64, BN=448 (v cols 0..383, logit cols 384..447).
// A read ONCE from fp32 x, converted in-reg (T14 prefetch), stored to
// padded As[64][40] (conflict-free ds_write). B staged per K-step via
// glds16 from L2-resident Wcat. Wave w owns rows [bm+16w, +16), all cols.
// Epilogue: v-cols -> bf16 v; logit cols -> LDS softmax -> attn.
// ---------------------------------------------------------------------------
__global__ __launch_bounds__(256) void gemm_v_logit_kernel(
    const float* __restrict__ X, const __bf16* __restrict__ Wcat,
    const float* __restrict__ b_v, __bf16* __restrict__ v,
    const float* __restrict__ bpad, float* __restrict__ attn) {
  __shared__ char smem[33792];
  __bf16 (*As)[40] = (__bf16(*)[40])smem;                 // 64x40x2 = 5120B
  __bf16 (*Bs)[32] = (__bf16(*)[32])(smem + 5120);        // 448x32x2 = 28672B
  float (*Ls)[68]  = (float(*)[68])smem;                  // overlay, 17408B

  const int tid  = threadIdx.x;
  const int wave = tid >> 6;
  const int lane = tid & 63;
  const int bm   = blockIdx.x * 64;
  const int srow  = lane >> 2;        // staging row within wave's 16
  const int skoff = (lane & 3) * 8;   // staging k offset
  const int frow  = lane & 15;
  const int fk    = (lane >> 4) * 8;
  const size_t xrow = (size_t)(bm + wave * 16 + srow) * CDIM;

  f32x4 acc[28] = {};

  // prefetch A chunk for ks=0
  float4 pa0 = *(const float4*)(X + xrow + skoff);
  float4 pa1 = *(const float4*)(X + xrow + skoff + 4);

  for (int ks = 0; ks < 12; ++ks) {
    const int k0 = ks * 32;
    // B-stage: 7 x 16-row chunks per wave (async)
    #pragma unroll
    for (int c = 0; c < 7; ++c) {
      const int brow = wave * 112 + c * 16;
      glds16(Wcat + (size_t)(brow + srow) * CDIM + k0 + skoff, &Bs[brow][0]);
    }
    // convert prefetched A, write to padded LDS
    bf16x8 h;
    h[0] = (__bf16)pa0.x; h[1] = (__bf16)pa0.y; h[2] = (__bf16)pa0.z; h[3] = (__bf16)pa0.w;
    h[4] = (__bf16)pa1.x; h[5] = (__bf16)pa1.y; h[6] = (__bf16)pa1.z; h[7] = (__bf16)pa1.w;
    *(bf16x8*)&As[wave * 16 + srow][skoff] = h;
    // prefetch next A chunk (lands during MFMA phase)
    if (ks < 11) {
      pa0 = *(const float4*)(X + xrow + k0 + 32 + skoff);
      pa1 = *(const float4*)(X + xrow + k0 + 36 + skoff);
    }
    __syncthreads();

    const bf16x8 a = *(const bf16x8*)&As[wave * 16 + frow][fk];
    #pragma unroll
    for (int ni = 0; ni < 28; ++ni) {
      const bf16x8 b = *(const bf16x8*)&Bs[ni * 16 + frow][fk];
      acc[ni] = __builtin_amdgcn_mfma_f32_16x16x32_bf16(a, b, acc[ni], 0, 0, 0);
    }
    __syncthreads();
  }

  const int orow = (lane >> 4) * 4;

  // v epilogue: cols 0..383
  #pragma unroll
  for (int ni = 0; ni < 24; ++ni) {
    const int n = ni * 16 + frow;
    const float bvl = b_v[n];
    #pragma unroll
    for (int r = 0; r < 4; ++r) {
      const int m = bm + wave * 16 + orow + r;
      v[(size_t)m * CDIM + n] = (__bf16)(acc[ni][r] + bvl);
    }
  }

  // logit epilogue: cols 384..447 -> Ls (overlay; all LDS reads done)
  float bvl[4];
  #pragma unroll
  for (int ni = 0; ni < 4; ++ni) bvl[ni] = bpad[ni * 16 + frow];
  #pragma unroll
  for (int ni = 0; ni < 4; ++ni)
    #pragma unroll
    for (int r = 0; r < 4; ++r)
      Ls[wave * 16 + orow + r][ni * 16 + frow] = acc[24 + ni][r] + bvl[ni];
  __syncthreads();

  // softmax: 64 pixels x 6 heads = 384 tasks
  #pragma unroll
  for (int it = 0; it < 2; ++it) {
    const int task = it * 256 + tid;
    if (task < 64 * HEADS) {
      const int pl = task / HEADS;
      const int h  = task % HEADS;
      const float* row = &Ls[pl][h * 9];
      float m = row[0];
      #pragma unroll
      for (int w = 1; w < 9; ++w) m = fmaxf(m, row[w]);
      float e[9], s = 0.f;
      #pragma unroll
      for (int w = 0; w < 9; ++w) { e[w] = __expf(row[w] - m); s += e[w]; }
      const float inv = 1.f / s;
      float* op = &attn[(size_t)(bm + pl) * NLOGIT + h * 9];
      #pragma unroll
      for (int w = 0; w < 9; ++w) op[w] = e[w] * inv;
    }
  }
}

// ---------------------------------------------------------------------------
// Proj GEMM, full-N: BM=64, BN=384. A (y, bf16) read once via glds16.
// Out fp32 = y @ Wtp^T + b_proj.
// ---------------------------------------------------------------------------
__global__ __launch_bounds__(256) void gemm_proj_kernel(
    const __bf16* __restrict__ A, const __bf16* __restrict__ Bt,
    const float* __restrict__ bias, float* __restrict__ Out) {
  __shared__ __bf16 As[64][32];    // 4096B
  __shared__ __bf16 Bs[384][32];   // 24576B

  const int tid  = threadIdx.x;
  const int wave = tid >> 6;
  const int lane = tid & 63;
  const int bm   = blockIdx.x * 64;
  const int srow  = lane >> 2;
  const int skoff = (lane & 3) * 8;
  const int frow  = lane & 15;
  const int fk    = (lane >> 4) * 8;

  f32x4 acc[24] = {};

  for (int ks = 0; ks < 12; ++ks) {
    const int k0 = ks * 32;
    glds16(A + (size_t)(bm + wave * 16 + srow) * CDIM + k0 + skoff,
           &As[wave * 16][0]);
    #pragma unroll
    for (int c = 0; c < 6; ++c) {
      const int brow = wave * 96 + c * 16;
      glds16(Bt + (size_t)(brow + srow) * CDIM + k0 + skoff, &Bs[brow][0]);
    }
    __syncthreads();

    const bf16x8 a = *(const bf16x8*)&As[wave * 16 + frow][fk];
    #pragma unroll
    for (int ni = 0; ni < 24; ++ni) {
      const bf16x8 b = *(const bf16x8*)&Bs[ni * 16 + frow][fk];
      acc[ni] = __builtin_amdgcn_mfma_f32_16x16x32_bf16(a, b, acc[ni], 0, 0, 0);
    }
    __syncthreads();
  }

  const int orow = (lane >> 4) * 4;
  #pragma unroll
  for (int ni = 0; ni < 24; ++ni) {
    const int n = ni * 16 + frow;
    const float bvl = bias[n];
    #pragma unroll
    for (int r = 0; r < 4; ++r) {
      const int m = bm + wave * 16 + orow + r;
      Out[(size_t)m * CDIM + n] = acc[ni][r] + bvl;
    }
  }
}

// ---------------------------------------------------------------------------
// Window aggregation, 4 vertically-adjacent pixels per thread (R8 version).
// ---------------------------------------------------------------------------
__global__ __launch_bounds__(256) void aggregate_kernel(
    const __bf16* __restrict__ v, const float* __restrict__ attn,
    __bf16* __restrict__ y) {
  const int idx = blockIdx.x * 256 + threadIdx.x;  // NPIX/4 * 48 = 602112
  const int cg = idx % 48;
  const int pg = idx / 48;
  const int c  = cg * 8;
  const int b  = pg / ((HH / 4) * WW);
  const int r2 = pg % ((HH / 4) * WW);
  const int i0 = (r2 / WW) * 4;
  const int j  = r2 % WW;
  const int head = c >> 6;

  const int pbase = (b * HH + i0) * WW + j;
  float aw[4][9];
  #pragma unroll
  for (int p = 0; p < 4; ++p) {
    const float* ap = attn + (size_t)(pbase + p * WW) * NLOGIT + head * 9;
    #pragma unroll
    for (int w = 0; w < 9; ++w) aw[p][w] = ap[w];
  }

  const bool j0ok = (j > 0), j2ok = (j < WW - 1);
  float acc[4][8] = {};

  #pragma unroll
  for (int li = 0; li < 6; ++li) {
    const int ii = i0 - 1 + li;
    if (ii < 0 || ii >= HH) continue;
    const __bf16* vrow = v + ((size_t)(b * HH + ii) * WW + j) * CDIM + c;
    float ch[3][8];
    #pragma unroll
    for (int kj = 0; kj < 3; ++kj) {
      const bool ok = (kj == 0) ? j0ok : (kj == 2) ? j2ok : true;
      if (ok) {
        const bf16x8 vv = *(const bf16x8*)(vrow + (kj - 1) * CDIM);
        #pragma unroll
        for (int q = 0; q < 8; ++q) ch[kj][q] = (float)vv[q];
      } else {
        #pragma unroll
        for (int q = 0; q < 8; ++q) ch[kj][q] = 0.f;
      }
    }
    #pragma unroll
    for (int p = 0; p < 4; ++p) {
      const int ki = li - p;
      if (ki < 0 || ki > 2) continue;
      #pragma unroll
      for (int kj = 0; kj < 3; ++kj) {
        const float w = aw[p][ki * 3 + kj];
        #pragma unroll
        for (int q = 0; q < 8; ++q) acc[p][q] += w * ch[kj][q];
      }
    }
  }

  #pragma unroll
  for (int p = 0; p < 4; ++p) {
    bf16x8 o;
    #pragma unroll
    for (int q = 0; q < 8; ++q) o[q] = (__bf16)acc[p][q];
    *(bf16x8*)&y[(size_t)(pbase + p * WW) * CDIM + c] = o;
  }
}

// ---------------------------------------------------------------------------
extern "C" void kernel_launch(void* const* d_in, const int* in_sizes, int n_in,
                              void* d_out, int out_size, void* d_ws,
                              size_t ws_size, hipStream_t stream) {
  const float* x      = (const float*)d_in[0];
  const float* W_attn = (const float*)d_in[1];
  const float* b_attn = (const float*)d_in[2];
  const float* W_v    = (const float*)d_in[3];
  const float* b_v    = (const float*)d_in[4];
  const float* W_proj = (const float*)d_in[5];
  const float* b_proj = (const float*)d_in[6];
  float* out = (float*)d_out;

  char* w = (char*)d_ws;
  __bf16* v    = (__bf16*)w;  w += (size_t)NPIX * CDIM * 2;   // 38.5MB
  __bf16* y    = (__bf16*)w;  w += (size_t)NPIX * CDIM * 2;   // 38.5MB
  float*  attn = (float*)w;   w += (size_t)NPIX * NLOGIT * 4; // 10.8MB
  __bf16* Wcat = (__bf16*)w;  w += (size_t)NCAT * CDIM * 2;   // 344KB
  __bf16* Wtp  = (__bf16*)w;  w += (size_t)CDIM * CDIM * 2;   // 288KB
  float*  bpad = (float*)w;   w += 64 * 4;

  // prep (one dispatch)
  const int prep_n = NCAT * CDIM + CDIM * CDIM + 64;
  prep_kernel<<<(prep_n + 255) / 256, 256, 0, stream>>>(
      W_v, W_proj, W_attn, b_attn, Wcat, Wtp, bpad);

  // 1. merged full-N: v-GEMM + logits/softmax (reads fp32 x once)
  gemm_v_logit_kernel<<<NPIX / 64, 256, 0, stream>>>(
      x, Wcat, b_v, v, bpad, attn);

  // 2. window aggregation -> y (bf16), 4 px/thread
  aggregate_kernel<<<(NPIX / 4 * 48) / 256, 256, 0, stream>>>(v, attn, y);

  // 3. out = y @ Wtp^T + b_proj (fp32 out), full-N
  gemm_proj_kernel<<<NPIX / 64, 256, 0, stream>>>(y, Wtp, b_proj, out);
}

// Round 12
// 118.090 us; speedup vs baseline: 2.1441x; 1.0111x over previous
//
#include <hip/hip_runtime.h>
#include <math.h>

#define NPIX 50176      // 16*56*56
#define CDIM 384
#define HEADS 6
#define NLOGIT 54       // HEADS*9
#define HH 56
#define WW 56
#define NCAT 448        // 384 v-cols + 64 padded logit cols
#define KSTEPS 12       // CDIM/32
#define NCH_V 28        // NCAT/16 fragment chunks
#define NCH_P 24        // CDIM/16 fragment chunks

typedef __attribute__((ext_vector_type(8))) __bf16 bf16x8;
typedef __attribute__((ext_vector_type(4))) float f32x4;

__device__ __forceinline__ void glds16(const void* g, void* l) {
  __builtin_amdgcn_global_load_lds(
      (const __attribute__((address_space(1))) unsigned int*)g,
      (__attribute__((address_space(3))) unsigned int*)l, 16, 0, 0);
}

// ---------------------------------------------------------------------------
// Prep: build fragment-major weights.
// Wcat_frag chunk (ks, ni, lane) holds 8 bf16: B^T[n=ni*16+(lane&15)]
//   [k=ks*32+(lane>>4)*8+q], where cols n<384 = W_v, 384+nn (nn<54) = W_attn,
//   else 0. Wtp_frag likewise for W_proj (24 chunks). bpad[64].
// One bf16x8 chunk per thread.
// ---------------------------------------------------------------------------
__global__ __launch_bounds__(256) void prep_kernel(
    const float* __restrict__ W_v, const float* __restrict__ W_proj,
    const float* __restrict__ W_attn, const float* __restrict__ b_attn,
    __bf16* __restrict__ Wcat_frag, __bf16* __restrict__ Wtp_frag,
    float* __restrict__ bpad) {
  const int gid = blockIdx.x * 256 + threadIdx.x;
  const int NV = KSTEPS * NCH_V * 64;   // 21504
  const int NP = KSTEPS * NCH_P * 64;   // 18432
  if (gid < NV) {
    const int ks   = gid / (NCH_V * 64);
    const int rem  = gid % (NCH_V * 64);
    const int ni   = rem >> 6;
    const int lane = rem & 63;
    const int n  = ni * 16 + (lane & 15);
    const int kb = ks * 32 + (lane >> 4) * 8;
    bf16x8 o;
    #pragma unroll
    for (int q = 0; q < 8; ++q) {
      const int k = kb + q;
      float val;
      if (n < CDIM) val = W_v[k * CDIM + n];
      else {
        const int nn = n - CDIM;
        val = (nn < NLOGIT) ? W_attn[k * NLOGIT + nn] : 0.f;
      }
      o[q] = (__bf16)val;
    }
    *(bf16x8*)&Wcat_frag[(size_t)gid * 8] = o;
  } else if (gid < NV + NP) {
    const int r    = gid - NV;
    const int ks   = r / (NCH_P * 64);
    const int rem  = r % (NCH_P * 64);
    const int ni   = rem >> 6;
    const int lane = rem & 63;
    const int n  = ni * 16 + (lane & 15);
    const int kb = ks * 32 + (lane >> 4) * 8;
    bf16x8 o;
    #pragma unroll
    for (int q = 0; q < 8; ++q) o[q] = (__bf16)W_proj[(kb + q) * CDIM + n];
    *(bf16x8*)&Wtp_frag[(size_t)r * 8] = o;
  } else if (gid < NV + NP + 64) {
    const int n = gid - NV - NP;
    bpad[n] = (n < NLOGIT) ? b_attn[n] : 0.f;
  }
}

// ---------------------------------------------------------------------------
// Merged full-N GEMM: BM=64, BN=448. A fragments loaded per-lane straight
// from fp32 x (cvt in reg, prefetched 1 K-step ahead) -- no A LDS at all.
// B staged fragment-major via glds16 (linear, conflict-free reads).
// Epilogue: cols 0..383 -> bf16 v; cols 384..447 -> softmax -> attn.
// ---------------------------------------------------------------------------
__global__ __launch_bounds__(256) void gemm_v_logit_kernel(
    const float* __restrict__ X, const __bf16* __restrict__ Wcat_frag,
    const float* __restrict__ b_v, __bf16* __restrict__ v,
    const float* __restrict__ bpad, float* __restrict__ attn) {
  __shared__ char smem[NCH_V * 1024];            // 28672B Bs; Ls overlay
  __bf16* Bs = (__bf16*)smem;
  float (*Ls)[68] = (float(*)[68])smem;          // 64x68 f32 = 17408B

  const int tid  = threadIdx.x;
  const int wave = tid >> 6;
  const int lane = tid & 63;
  const int bm   = blockIdx.x * 64;
  const int frow = lane & 15;
  const int fk8  = (lane >> 4) * 8;

  const int arow = bm + wave * 16 + frow;
  const float* xrow = X + (size_t)arow * CDIM + fk8;

  f32x4 acc[28] = {};
  float4 pa0 = *(const float4*)(xrow + 0);
  float4 pa1 = *(const float4*)(xrow + 4);

  for (int ks = 0; ks < KSTEPS; ++ks) {
    // stage B fragment-major: 7 chunks/wave, linear src and dest
    #pragma unroll
    for (int c = 0; c < 7; ++c) {
      const int chunk = wave * 7 + c;
      glds16(Wcat_frag + ((size_t)(ks * NCH_V + chunk) * 64 + lane) * 8,
             Bs + chunk * 512);
    }
    // convert prefetched A fragment
    bf16x8 a;
    a[0] = (__bf16)pa0.x; a[1] = (__bf16)pa0.y; a[2] = (__bf16)pa0.z; a[3] = (__bf16)pa0.w;
    a[4] = (__bf16)pa1.x; a[5] = (__bf16)pa1.y; a[6] = (__bf16)pa1.z; a[7] = (__bf16)pa1.w;
    if (ks < KSTEPS - 1) {
      pa0 = *(const float4*)(xrow + (ks + 1) * 32 + 0);
      pa1 = *(const float4*)(xrow + (ks + 1) * 32 + 4);
    }
    __syncthreads();

    #pragma unroll
    for (int ni = 0; ni < 28; ++ni) {
      const bf16x8 b = *(const bf16x8*)&Bs[(ni * 64 + lane) * 8];
      acc[ni] = __builtin_amdgcn_mfma_f32_16x16x32_bf16(a, b, acc[ni], 0, 0, 0);
    }
    __syncthreads();
  }

  const int orow = (lane >> 4) * 4;

  // v epilogue: cols 0..383
  #pragma unroll
  for (int ni = 0; ni < 24; ++ni) {
    const int n = ni * 16 + frow;
    const float bvl = b_v[n];
    #pragma unroll
    for (int r = 0; r < 4; ++r) {
      const int m = bm + wave * 16 + orow + r;
      v[(size_t)m * CDIM + n] = (__bf16)(acc[ni][r] + bvl);
    }
  }

  // logit epilogue: cols 384..447 -> Ls -> softmax -> attn
  float bvl[4];
  #pragma unroll
  for (int ni = 0; ni < 4; ++ni) bvl[ni] = bpad[ni * 16 + frow];
  #pragma unroll
  for (int ni = 0; ni < 4; ++ni)
    #pragma unroll
    for (int r = 0; r < 4; ++r)
      Ls[wave * 16 + orow + r][ni * 16 + frow] = acc[24 + ni][r] + bvl[ni];
  __syncthreads();

  #pragma unroll
  for (int it = 0; it < 2; ++it) {
    const int task = it * 256 + tid;
    if (task < 64 * HEADS) {
      const int pl = task / HEADS;
      const int h  = task % HEADS;
      const float* row = &Ls[pl][h * 9];
      float m = row[0];
      #pragma unroll
      for (int w = 1; w < 9; ++w) m = fmaxf(m, row[w]);
      float e[9], s = 0.f;
      #pragma unroll
      for (int w = 0; w < 9; ++w) { e[w] = __expf(row[w] - m); s += e[w]; }
      const float inv = 1.f / s;
      float* op = &attn[(size_t)(bm + pl) * NLOGIT + h * 9];
      #pragma unroll
      for (int w = 0; w < 9; ++w) op[w] = e[w] * inv;
    }
  }
}

// ---------------------------------------------------------------------------
// Proj GEMM, full-N: BM=64, BN=384. A (y bf16) fragments per-lane from
// global (prefetched); B fragment-major staged, conflict-free. Out fp32.
// ---------------------------------------------------------------------------
__global__ __launch_bounds__(256) void gemm_proj_kernel(
    const __bf16* __restrict__ Y, const __bf16* __restrict__ Wtp_frag,
    const float* __restrict__ bias, float* __restrict__ Out) {
  __shared__ __bf16 Bs[NCH_P * 512];   // 24576B

  const int tid  = threadIdx.x;
  const int wave = tid >> 6;
  const int lane = tid & 63;
  const int bm   = blockIdx.x * 64;
  const int frow = lane & 15;
  const int fk8  = (lane >> 4) * 8;

  const int arow = bm + wave * 16 + frow;
  const __bf16* yrow = Y + (size_t)arow * CDIM + fk8;

  f32x4 acc[24] = {};
  bf16x8 a = *(const bf16x8*)(yrow);

  for (int ks = 0; ks < KSTEPS; ++ks) {
    #pragma unroll
    for (int c = 0; c < 6; ++c) {
      const int chunk = wave * 6 + c;
      glds16(Wtp_frag + ((size_t)(ks * NCH_P + chunk) * 64 + lane) * 8,
             Bs + chunk * 512);
    }
    bf16x8 a_next;
    if (ks < KSTEPS - 1) a_next = *(const bf16x8*)(yrow + (ks + 1) * 32);
    __syncthreads();

    #pragma unroll
    for (int ni = 0; ni < 24; ++ni) {
      const bf16x8 b = *(const bf16x8*)&Bs[(ni * 64 + lane) * 8];
      acc[ni] = __builtin_amdgcn_mfma_f32_16x16x32_bf16(a, b, acc[ni], 0, 0, 0);
    }
    __syncthreads();
    a = a_next;
  }

  const int orow = (lane >> 4) * 4;
  #pragma unroll
  for (int ni = 0; ni < 24; ++ni) {
    const int n = ni * 16 + frow;
    const float bvl = bias[n];
    #pragma unroll
    for (int r = 0; r < 4; ++r) {
      const int m = bm + wave * 16 + orow + r;
      Out[(size_t)m * CDIM + n] = acc[ni][r] + bvl;
    }
  }
}

// ---------------------------------------------------------------------------
// Window aggregation, 4 vertically-adjacent pixels per thread.
// ---------------------------------------------------------------------------
__global__ __launch_bounds__(256) void aggregate_kernel(
    const __bf16* __restrict__ v, const float* __restrict__ attn,
    __bf16* __restrict__ y) {
  const int idx = blockIdx.x * 256 + threadIdx.x;  // NPIX/4 * 48 = 602112
  const int cg = idx % 48;
  const int pg = idx / 48;
  const int c  = cg * 8;
  const int b  = pg / ((HH / 4) * WW);
  const int r2 = pg % ((HH / 4) * WW);
  const int i0 = (r2 / WW) * 4;
  const int j  = r2 % WW;
  const int head = c >> 6;

  const int pbase = (b * HH + i0) * WW + j;
  float aw[4][9];
  #pragma unroll
  for (int p = 0; p < 4; ++p) {
    const float* ap = attn + (size_t)(pbase + p * WW) * NLOGIT + head * 9;
    #pragma unroll
    for (int w = 0; w < 9; ++w) aw[p][w] = ap[w];
  }

  const bool j0ok = (j > 0), j2ok = (j < WW - 1);
  float acc[4][8] = {};

  #pragma unroll
  for (int li = 0; li < 6; ++li) {
    const int ii = i0 - 1 + li;
    if (ii < 0 || ii >= HH) continue;
    const __bf16* vrow = v + ((size_t)(b * HH + ii) * WW + j) * CDIM + c;
    float ch[3][8];
    #pragma unroll
    for (int kj = 0; kj < 3; ++kj) {
      const bool ok = (kj == 0) ? j0ok : (kj == 2) ? j2ok : true;
      if (ok) {
        const bf16x8 vv = *(const bf16x8*)(vrow + (kj - 1) * CDIM);
        #pragma unroll
        for (int q = 0; q < 8; ++q) ch[kj][q] = (float)vv[q];
      } else {
        #pragma unroll
        for (int q = 0; q < 8; ++q) ch[kj][q] = 0.f;
      }
    }
    #pragma unroll
    for (int p = 0; p < 4; ++p) {
      const int ki = li - p;
      if (ki < 0 || ki > 2) continue;
      #pragma unroll
      for (int kj = 0; kj < 3; ++kj) {
        const float w = aw[p][ki * 3 + kj];
        #pragma unroll
        for (int q = 0; q < 8; ++q) acc[p][q] += w * ch[kj][q];
      }
    }
  }

  #pragma unroll
  for (int p = 0; p < 4; ++p) {
    bf16x8 o;
    #pragma unroll
    for (int q = 0; q < 8; ++q) o[q] = (__bf16)acc[p][q];
    *(bf16x8*)&y[(size_t)(pbase + p * WW) * CDIM + c] = o;
  }
}

// ---------------------------------------------------------------------------
extern "C" void kernel_launch(void* const* d_in, const int* in_sizes, int n_in,
                              void* d_out, int out_size, void* d_ws,
                              size_t ws_size, hipStream_t stream) {
  const float* x      = (const float*)d_in[0];
  const float* W_attn = (const float*)d_in[1];
  const float* b_attn = (const float*)d_in[2];
  const float* W_v    = (const float*)d_in[3];
  const float* b_v    = (const float*)d_in[4];
  const float* W_proj = (const float*)d_in[5];
  const float* b_proj = (const float*)d_in[6];
  float* out = (float*)d_out;

  char* w = (char*)d_ws;
  __bf16* v    = (__bf16*)w;  w += (size_t)NPIX * CDIM * 2;   // 38.5MB
  __bf16* y    = (__bf16*)w;  w += (size_t)NPIX * CDIM * 2;   // 38.5MB
  float*  attn = (float*)w;   w += (size_t)NPIX * NLOGIT * 4; // 10.8MB
  __bf16* Wcat_frag = (__bf16*)w;  w += (size_t)NCAT * CDIM * 2;  // 344KB
  __bf16* Wtp_frag  = (__bf16*)w;  w += (size_t)CDIM * CDIM * 2;  // 288KB
  float*  bpad = (float*)w;   w += 64 * 4;

  // prep (one dispatch): fragment-major weights
  const int prep_n = KSTEPS * NCH_V * 64 + KSTEPS * NCH_P * 64 + 64;
  prep_kernel<<<(prep_n + 255) / 256, 256, 0, stream>>>(
      W_v, W_proj, W_attn, b_attn, Wcat_frag, Wtp_frag, bpad);

  // 1. merged full-N: v-GEMM + logits/softmax (reads fp32 x once)
  gemm_v_logit_kernel<<<NPIX / 64, 256, 0, stream>>>(
      x, Wcat_frag, b_v, v, bpad, attn);

  // 2. window aggregation -> y (bf16), 4 px/thread
  aggregate_kernel<<<(NPIX / 4 * 48) / 256, 256, 0, stream>>>(v, attn, y);

  // 3. out = y @ Wtp^T + b_proj (fp32 out), full-N
  gemm_proj_kernel<<<NPIX / 64, 256, 0, stream>>>(y, Wtp_frag, b_proj, out);
}

// Round 13
// 108.217 us; speedup vs baseline: 2.3397x; 1.0912x over previous
//
#include <hip/hip_runtime.h>
#include <math.h>

#define NPIX 50176      // 16*56*56
#define CDIM 384
#define HEADS 6
#define NLOGIT 54       // HEADS*9
#define HH 56
#define WW 56
#define NCAT 448        // 384 v-cols + 64 padded logit cols
#define KSTEPS 12       // CDIM/32
#define NCH_V 28        // NCAT/16 fragment chunks (total)
#define NCH_P 24        // CDIM/16 fragment chunks (total)

typedef __attribute__((ext_vector_type(8))) __bf16 bf16x8;
typedef __attribute__((ext_vector_type(4))) float f32x4;

__device__ __forceinline__ void glds16(const void* g, void* l) {
  __builtin_amdgcn_global_load_lds(
      (const __attribute__((address_space(1))) unsigned int*)g,
      (__attribute__((address_space(3))) unsigned int*)l, 16, 0, 0);
}

// ---------------------------------------------------------------------------
// Prep: fragment-major weights (unchanged from R12).
// Wcat_frag chunk (ks, ni, lane): 8 bf16 of B^T[n=ni*16+(lane&15)]
//   [k=ks*32+(lane>>4)*8+q]; n<384 = W_v, 384+nn<54 = W_attn, else 0.
// Wtp_frag likewise for W_proj. bpad[64].
// ---------------------------------------------------------------------------
__global__ __launch_bounds__(256) void prep_kernel(
    const float* __restrict__ W_v, const float* __restrict__ W_proj,
    const float* __restrict__ W_attn, const float* __restrict__ b_attn,
    __bf16* __restrict__ Wcat_frag, __bf16* __restrict__ Wtp_frag,
    float* __restrict__ bpad) {
  const int gid = blockIdx.x * 256 + threadIdx.x;
  const int NV = KSTEPS * NCH_V * 64;   // 21504
  const int NP = KSTEPS * NCH_P * 64;   // 18432
  if (gid < NV) {
    const int ks   = gid / (NCH_V * 64);
    const int rem  = gid % (NCH_V * 64);
    const int ni   = rem >> 6;
    const int lane = rem & 63;
    const int n  = ni * 16 + (lane & 15);
    const int kb = ks * 32 + (lane >> 4) * 8;
    bf16x8 o;
    #pragma unroll
    for (int q = 0; q < 8; ++q) {
      const int k = kb + q;
      float val;
      if (n < CDIM) val = W_v[k * CDIM + n];
      else {
        const int nn = n - CDIM;
        val = (nn < NLOGIT) ? W_attn[k * NLOGIT + nn] : 0.f;
      }
      o[q] = (__bf16)val;
    }
    *(bf16x8*)&Wcat_frag[(size_t)gid * 8] = o;
  } else if (gid < NV + NP) {
    const int r    = gid - NV;
    const int ks   = r / (NCH_P * 64);
    const int rem  = r % (NCH_P * 64);
    const int ni   = rem >> 6;
    const int lane = rem & 63;
    const int n  = ni * 16 + (lane & 15);
    const int kb = ks * 32 + (lane >> 4) * 8;
    bf16x8 o;
    #pragma unroll
    for (int q = 0; q < 8; ++q) o[q] = (__bf16)W_proj[(kb + q) * CDIM + n];
    *(bf16x8*)&Wtp_frag[(size_t)r * 8] = o;
  } else if (gid < NV + NP + 64) {
    const int n = gid - NV - NP;
    bpad[n] = (n < NLOGIT) ? b_attn[n] : 0.f;
  }
}

// ---------------------------------------------------------------------------
// Merged GEMM, N split in half: grid (NPIX/64, 2). Block by owns 14 chunks
// (cols by*224 .. +224). Double-buffered B-stage: glds16 for ks+1 issued
// before the MFMA phase of ks -> stage latency hidden. acc[14] (56 regs).
// by==1 chunks 10..13 are the logit cols -> softmax -> attn.
// ---------------------------------------------------------------------------
__global__ __launch_bounds__(256) void gemm_v_logit_kernel(
    const float* __restrict__ X, const __bf16* __restrict__ Wcat_frag,
    const float* __restrict__ b_v, __bf16* __restrict__ v,
    const float* __restrict__ bpad, float* __restrict__ attn) {
  __shared__ char smem[2 * 14 * 1024];           // 28672B: 2 x 14-chunk buf
  float (*Ls)[68] = (float(*)[68])smem;          // overlay (17408B)

  const int tid  = threadIdx.x;
  const int wave = tid >> 6;
  const int lane = tid & 63;
  const int bm   = blockIdx.x * 64;
  const int by   = blockIdx.y;                   // 0 or 1
  const int nbase = by * 14;                     // chunk offset
  const int frow = lane & 15;
  const int fk8  = (lane >> 4) * 8;

  const int arow = bm + wave * 16 + frow;
  const float* xrow = X + (size_t)arow * CDIM + fk8;

  f32x4 acc[14] = {};

  // prologue: stage ks=0 into buf0, prefetch A(0)
  #pragma unroll
  for (int c = 0; c < 4; ++c) {
    const int chunk = wave * 4 + c;
    if (chunk < 14)
      glds16(Wcat_frag + ((size_t)(0 * NCH_V + nbase + chunk) * 64 + lane) * 8,
             (__bf16*)smem + chunk * 512);
  }
  float4 pa0 = *(const float4*)(xrow + 0);
  float4 pa1 = *(const float4*)(xrow + 4);
  __syncthreads();

  int buf = 0;
  for (int ks = 0; ks < KSTEPS; ++ks) {
    // issue next-step B stage into the other buffer (async, overlaps MFMA)
    if (ks + 1 < KSTEPS) {
      __bf16* dst = (__bf16*)smem + (buf ^ 1) * 14 * 512;
      #pragma unroll
      for (int c = 0; c < 4; ++c) {
        const int chunk = wave * 4 + c;
        if (chunk < 14)
          glds16(Wcat_frag +
                     ((size_t)((ks + 1) * NCH_V + nbase + chunk) * 64 + lane) * 8,
                 dst + chunk * 512);
      }
    }
    // convert prefetched A; prefetch next
    bf16x8 a;
    a[0] = (__bf16)pa0.x; a[1] = (__bf16)pa0.y; a[2] = (__bf16)pa0.z; a[3] = (__bf16)pa0.w;
    a[4] = (__bf16)pa1.x; a[5] = (__bf16)pa1.y; a[6] = (__bf16)pa1.z; a[7] = (__bf16)pa1.w;
    if (ks + 1 < KSTEPS) {
      pa0 = *(const float4*)(xrow + (ks + 1) * 32 + 0);
      pa1 = *(const float4*)(xrow + (ks + 1) * 32 + 4);
    }

    const __bf16* Bc = (const __bf16*)smem + buf * 14 * 512;
    #pragma unroll
    for (int ni = 0; ni < 14; ++ni) {
      const bf16x8 b = *(const bf16x8*)&Bc[(ni * 64 + lane) * 8];
      acc[ni] = __builtin_amdgcn_mfma_f32_16x16x32_bf16(a, b, acc[ni], 0, 0, 0);
    }
    __syncthreads();   // drains next-step glds16 (overlapped) + read fence
    buf ^= 1;
  }

  const int orow = (lane >> 4) * 4;
  const int nv = (by == 0) ? 14 : 10;   // v chunks this block

  #pragma unroll
  for (int ni = 0; ni < 14; ++ni) {
    if (ni < nv) {
      const int n = by * 224 + ni * 16 + frow;
      const float bvl = b_v[n];
      #pragma unroll
      for (int r = 0; r < 4; ++r) {
        const int m = bm + wave * 16 + orow + r;
        v[(size_t)m * CDIM + n] = (__bf16)(acc[ni][r] + bvl);
      }
    }
  }

  if (by == 1) {
    // logit chunks 10..13 -> Ls -> softmax -> attn
    float bvl[4];
    #pragma unroll
    for (int ni = 0; ni < 4; ++ni) bvl[ni] = bpad[ni * 16 + frow];
    #pragma unroll
    for (int ni = 0; ni < 4; ++ni)
      #pragma unroll
      for (int r = 0; r < 4; ++r)
        Ls[wave * 16 + orow + r][ni * 16 + frow] = acc[10 + ni][r] + bvl[ni];
    __syncthreads();

    #pragma unroll
    for (int it = 0; it < 2; ++it) {
      const int task = it * 256 + tid;
      if (task < 64 * HEADS) {
        const int pl = task / HEADS;
        const int h  = task % HEADS;
        const float* row = &Ls[pl][h * 9];
        float m = row[0];
        #pragma unroll
        for (int w = 1; w < 9; ++w) m = fmaxf(m, row[w]);
        float e[9], s = 0.f;
        #pragma unroll
        for (int w = 0; w < 9; ++w) { e[w] = __expf(row[w] - m); s += e[w]; }
        const float inv = 1.f / s;
        float* op = &attn[(size_t)(bm + pl) * NLOGIT + h * 9];
        #pragma unroll
        for (int w = 0; w < 9; ++w) op[w] = e[w] * inv;
      }
    }
  }
}

// ---------------------------------------------------------------------------
// Proj GEMM, N split in half: grid (NPIX/64, 2), 12 chunks each, dbuf.
// A (y bf16) per-lane from global, prefetched. Out fp32.
// ---------------------------------------------------------------------------
__global__ __launch_bounds__(256) void gemm_proj_kernel(
    const __bf16* __restrict__ Y, const __bf16* __restrict__ Wtp_frag,
    const float* __restrict__ bias, float* __restrict__ Out) {
  __shared__ __bf16 Bs[2 * 12 * 512];   // 24576B

  const int tid  = threadIdx.x;
  const int wave = tid >> 6;
  const int lane = tid & 63;
  const int bm   = blockIdx.x * 64;
  const int by   = blockIdx.y;
  const int nbase = by * 12;
  const int frow = lane & 15;
  const int fk8  = (lane >> 4) * 8;

  const int arow = bm + wave * 16 + frow;
  const __bf16* yrow = Y + (size_t)arow * CDIM + fk8;

  f32x4 acc[12] = {};

  #pragma unroll
  for (int c = 0; c < 3; ++c) {
    const int chunk = wave * 3 + c;
    glds16(Wtp_frag + ((size_t)(nbase + chunk) * 64 + lane) * 8,
           Bs + chunk * 512);
  }
  bf16x8 a = *(const bf16x8*)(yrow);
  __syncthreads();

  int buf = 0;
  for (int ks = 0; ks < KSTEPS; ++ks) {
    if (ks + 1 < KSTEPS) {
      __bf16* dst = Bs + (buf ^ 1) * 12 * 512;
      #pragma unroll
      for (int c = 0; c < 3; ++c) {
        const int chunk = wave * 3 + c;
        glds16(Wtp_frag +
                   ((size_t)((ks + 1) * NCH_P + nbase + chunk) * 64 + lane) * 8,
               dst + chunk * 512);
      }
    }
    bf16x8 a_next;
    if (ks + 1 < KSTEPS) a_next = *(const bf16x8*)(yrow + (ks + 1) * 32);

    const __bf16* Bc = Bs + buf * 12 * 512;
    #pragma unroll
    for (int ni = 0; ni < 12; ++ni) {
      const bf16x8 b = *(const bf16x8*)&Bc[(ni * 64 + lane) * 8];
      acc[ni] = __builtin_amdgcn_mfma_f32_16x16x32_bf16(a, b, acc[ni], 0, 0, 0);
    }
    __syncthreads();
    buf ^= 1;
    a = a_next;
  }

  const int orow = (lane >> 4) * 4;
  #pragma unroll
  for (int ni = 0; ni < 12; ++ni) {
    const int n = by * 192 + ni * 16 + frow;
    const float bvl = bias[n];
    #pragma unroll
    for (int r = 0; r < 4; ++r) {
      const int m = bm + wave * 16 + orow + r;
      Out[(size_t)m * CDIM + n] = acc[ni][r] + bvl;
    }
  }
}

// ---------------------------------------------------------------------------
// Window aggregation, 4 vertically-adjacent pixels per thread (unchanged).
// ---------------------------------------------------------------------------
__global__ __launch_bounds__(256) void aggregate_kernel(
    const __bf16* __restrict__ v, const float* __restrict__ attn,
    __bf16* __restrict__ y) {
  const int idx = blockIdx.x * 256 + threadIdx.x;  // NPIX/4 * 48 = 602112
  const int cg = idx % 48;
  const int pg = idx / 48;
  const int c  = cg * 8;
  const int b  = pg / ((HH / 4) * WW);
  const int r2 = pg % ((HH / 4) * WW);
  const int i0 = (r2 / WW) * 4;
  const int j  = r2 % WW;
  const int head = c >> 6;

  const int pbase = (b * HH + i0) * WW + j;
  float aw[4][9];
  #pragma unroll
  for (int p = 0; p < 4; ++p) {
    const float* ap = attn + (size_t)(pbase + p * WW) * NLOGIT + head * 9;
    #pragma unroll
    for (int w = 0; w < 9; ++w) aw[p][w] = ap[w];
  }

  const bool j0ok = (j > 0), j2ok = (j < WW - 1);
  float acc[4][8] = {};

  #pragma unroll
  for (int li = 0; li < 6; ++li) {
    const int ii = i0 - 1 + li;
    if (ii < 0 || ii >= HH) continue;
    const __bf16* vrow = v + ((size_t)(b * HH + ii) * WW + j) * CDIM + c;
    float ch[3][8];
    #pragma unroll
    for (int kj = 0; kj < 3; ++kj) {
      const bool ok = (kj == 0) ? j0ok : (kj == 2) ? j2ok : true;
      if (ok) {
        const bf16x8 vv = *(const bf16x8*)(vrow + (kj - 1) * CDIM);
        #pragma unroll
        for (int q = 0; q < 8; ++q) ch[kj][q] = (float)vv[q];
      } else {
        #pragma unroll
        for (int q = 0; q < 8; ++q) ch[kj][q] = 0.f;
      }
    }
    #pragma unroll
    for (int p = 0; p < 4; ++p) {
      const int ki = li - p;
      if (ki < 0 || ki > 2) continue;
      #pragma unroll
      for (int kj = 0; kj < 3; ++kj) {
        const float w = aw[p][ki * 3 + kj];
        #pragma unroll
        for (int q = 0; q < 8; ++q) acc[p][q] += w * ch[kj][q];
      }
    }
  }

  #pragma unroll
  for (int p = 0; p < 4; ++p) {
    bf16x8 o;
    #pragma unroll
    for (int q = 0; q < 8; ++q) o[q] = (__bf16)acc[p][q];
    *(bf16x8*)&y[(size_t)(pbase + p * WW) * CDIM + c] = o;
  }
}

// ---------------------------------------------------------------------------
extern "C" void kernel_launch(void* const* d_in, const int* in_sizes, int n_in,
                              void* d_out, int out_size, void* d_ws,
                              size_t ws_size, hipStream_t stream) {
  const float* x      = (const float*)d_in[0];
  const float* W_attn = (const float*)d_in[1];
  const float* b_attn = (const float*)d_in[2];
  const float* W_v    = (const float*)d_in[3];
  const float* b_v    = (const float*)d_in[4];
  const float* W_proj = (const float*)d_in[5];
  const float* b_proj = (const float*)d_in[6];
  float* out = (float*)d_out;

  char* w = (char*)d_ws;
  __bf16* v    = (__bf16*)w;  w += (size_t)NPIX * CDIM * 2;   // 38.5MB
  __bf16* y    = (__bf16*)w;  w += (size_t)NPIX * CDIM * 2;   // 38.5MB
  float*  attn = (float*)w;   w += (size_t)NPIX * NLOGIT * 4; // 10.8MB
  __bf16* Wcat_frag = (__bf16*)w;  w += (size_t)NCAT * CDIM * 2;  // 344KB
  __bf16* Wtp_frag  = (__bf16*)w;  w += (size_t)CDIM * CDIM * 2;  // 288KB
  float*  bpad = (float*)w;   w += 64 * 4;

  // prep (one dispatch): fragment-major weights
  const int prep_n = KSTEPS * NCH_V * 64 + KSTEPS * NCH_P * 64 + 64;
  prep_kernel<<<(prep_n + 255) / 256, 256, 0, stream>>>(
      W_v, W_proj, W_attn, b_attn, Wcat_frag, Wtp_frag, bpad);

  // 1. merged split-N: v-GEMM + logits/softmax
  gemm_v_logit_kernel<<<dim3(NPIX / 64, 2), 256, 0, stream>>>(
      x, Wcat_frag, b_v, v, bpad, attn);

  // 2. window aggregation -> y (bf16), 4 px/thread
  aggregate_kernel<<<(NPIX / 4 * 48) / 256, 256, 0, stream>>>(v, attn, y);

  // 3. out = y @ Wtp^T + b_proj (fp32 out), split-N, dbuf
  gemm_proj_kernel<<<dim3(NPIX / 64, 2), 256, 0, stream>>>(
      y, Wtp_frag, b_proj, out);
}

// Round 14
// 105.356 us; speedup vs baseline: 2.4032x; 1.0271x over previous
//
#include <hip/hip_runtime.h>
#include <math.h>

#define NPIX 50176      // 16*56*56
#define CDIM 384
#define HEADS 6
#define NLOGIT 54       // HEADS*9
#define HH 56
#define WW 56
#define NCAT 448        // 384 v-cols + 64 padded logit cols
#define KSTEPS 12       // CDIM/32
#define NCH_V 28        // NCAT/16 fragment chunks (total)
#define NCH_P 24        // CDIM/16 fragment chunks (total)

typedef __attribute__((ext_vector_type(8))) __bf16 bf16x8;
typedef __attribute__((ext_vector_type(4))) float f32x4;

__device__ __forceinline__ void glds16(const void* g, void* l) {
  __builtin_amdgcn_global_load_lds(
      (const __attribute__((address_space(1))) unsigned int*)g,
      (__attribute__((address_space(3))) unsigned int*)l, 16, 0, 0);
}

// ---------------------------------------------------------------------------
// Prep: fragment-major weights (unchanged).
// ---------------------------------------------------------------------------
__global__ __launch_bounds__(256) void prep_kernel(
    const float* __restrict__ W_v, const float* __restrict__ W_proj,
    const float* __restrict__ W_attn, const float* __restrict__ b_attn,
    __bf16* __restrict__ Wcat_frag, __bf16* __restrict__ Wtp_frag,
    float* __restrict__ bpad) {
  const int gid = blockIdx.x * 256 + threadIdx.x;
  const int NV = KSTEPS * NCH_V * 64;   // 21504
  const int NP = KSTEPS * NCH_P * 64;   // 18432
  if (gid < NV) {
    const int ks   = gid / (NCH_V * 64);
    const int rem  = gid % (NCH_V * 64);
    const int ni   = rem >> 6;
    const int lane = rem & 63;
    const int n  = ni * 16 + (lane & 15);
    const int kb = ks * 32 + (lane >> 4) * 8;
    bf16x8 o;
    #pragma unroll
    for (int q = 0; q < 8; ++q) {
      const int k = kb + q;
      float val;
      if (n < CDIM) val = W_v[k * CDIM + n];
      else {
        const int nn = n - CDIM;
        val = (nn < NLOGIT) ? W_attn[k * NLOGIT + nn] : 0.f;
      }
      o[q] = (__bf16)val;
    }
    *(bf16x8*)&Wcat_frag[(size_t)gid * 8] = o;
  } else if (gid < NV + NP) {
    const int r    = gid - NV;
    const int ks   = r / (NCH_P * 64);
    const int rem  = r % (NCH_P * 64);
    const int ni   = rem >> 6;
    const int lane = rem & 63;
    const int n  = ni * 16 + (lane & 15);
    const int kb = ks * 32 + (lane >> 4) * 8;
    bf16x8 o;
    #pragma unroll
    for (int q = 0; q < 8; ++q) o[q] = (__bf16)W_proj[(kb + q) * CDIM + n];
    *(bf16x8*)&Wtp_frag[(size_t)r * 8] = o;
  } else if (gid < NV + NP + 64) {
    const int n = gid - NV - NP;
    bpad[n] = (n < NLOGIT) ? b_attn[n] : 0.f;
  }
}

// ---------------------------------------------------------------------------
// Merged GEMM, split-N (grid NPIX/64 x 2), T4 pipeline:
// triple-buffered B, counted s_waitcnt vmcnt(6) + raw s_barrier per K-step
// (never vmcnt(0) mid-loop). Per-iter per-wave vmem: 2 A-loads + 4 glds16.
// A fp32->bf16 in reg, prefetch depth 2. acc[14]. by==1 chunks 10..13 are
// logit cols -> softmax -> attn.
// ---------------------------------------------------------------------------
__global__ __launch_bounds__(256) void gemm_v_logit_kernel(
    const float* __restrict__ X, const __bf16* __restrict__ Wcat_frag,
    const float* __restrict__ b_v, __bf16* __restrict__ v,
    const float* __restrict__ bpad, float* __restrict__ attn) {
  __shared__ __bf16 Bs[3 * 14 * 512];            // 43008B, 3 bufs
  float (*Ls)[68] = (float(*)[68])Bs;            // overlay (epilogue only)

  const int tid  = threadIdx.x;
  const int wave = tid >> 6;
  const int lane = tid & 63;
  const int bm   = blockIdx.x * 64;
  const int by   = blockIdx.y;                   // 0 or 1
  const int nbase = by * 14;
  const int frow = lane & 15;
  const int fk8  = (lane >> 4) * 8;

  const int arow = bm + wave * 16 + frow;
  const float* xrow = X + (size_t)arow * CDIM + fk8;

  f32x4 acc[14] = {};
  float4 pa[2][2];

  // prologue: A(0), stage(0->buf0), A(1), stage(1->buf1)  (12 vmem/wave)
  pa[0][0] = *(const float4*)(xrow + 0);
  pa[0][1] = *(const float4*)(xrow + 4);
  #pragma unroll
  for (int c = 0; c < 4; ++c) {
    const int chunk = wave * 4 + c;
    if (chunk < 14)
      glds16(Wcat_frag + ((size_t)(nbase + chunk) * 64 + lane) * 8,
             Bs + chunk * 512);
  }
  pa[1][0] = *(const float4*)(xrow + 32);
  pa[1][1] = *(const float4*)(xrow + 36);
  #pragma unroll
  for (int c = 0; c < 4; ++c) {
    const int chunk = wave * 4 + c;
    if (chunk < 14)
      glds16(Wcat_frag + ((size_t)(NCH_V + nbase + chunk) * 64 + lane) * 8,
             Bs + 14 * 512 + chunk * 512);
  }

  #pragma unroll
  for (int ks = 0; ks < KSTEPS; ++ks) {
    // wait for OWN stage(ks) (6 newer vmem allowed), then raw barrier.
    if (ks < KSTEPS - 1) {
      asm volatile("s_waitcnt vmcnt(6)" ::: "memory");
    } else {
      asm volatile("s_waitcnt vmcnt(0)" ::: "memory");
    }
    __builtin_amdgcn_s_barrier();

    // convert A(ks) (loads are oldest -> already complete)
    const float4 q0 = pa[ks & 1][0], q1 = pa[ks & 1][1];
    bf16x8 a;
    a[0] = (__bf16)q0.x; a[1] = (__bf16)q0.y; a[2] = (__bf16)q0.z; a[3] = (__bf16)q0.w;
    a[4] = (__bf16)q1.x; a[5] = (__bf16)q1.y; a[6] = (__bf16)q1.z; a[7] = (__bf16)q1.w;

    // issue A(ks+2) then stage(ks+2) (6 vmem; overlap MFMA below)
    if (ks + 2 < KSTEPS) {
      pa[ks & 1][0] = *(const float4*)(xrow + (ks + 2) * 32 + 0);
      pa[ks & 1][1] = *(const float4*)(xrow + (ks + 2) * 32 + 4);
      __bf16* dst = Bs + ((ks + 2) % 3) * 14 * 512;
      #pragma unroll
      for (int c = 0; c < 4; ++c) {
        const int chunk = wave * 4 + c;
        if (chunk < 14)
          glds16(Wcat_frag +
                     ((size_t)((ks + 2) * NCH_V + nbase + chunk) * 64 + lane) * 8,
                 dst + chunk * 512);
      }
    }

    const __bf16* Bc = Bs + (ks % 3) * 14 * 512;
    #pragma unroll
    for (int ni = 0; ni < 14; ++ni) {
      const bf16x8 b = *(const bf16x8*)&Bc[(ni * 64 + lane) * 8];
      acc[ni] = __builtin_amdgcn_mfma_f32_16x16x32_bf16(a, b, acc[ni], 0, 0, 0);
    }
  }

  const int orow = (lane >> 4) * 4;
  const int nv = (by == 0) ? 14 : 10;

  #pragma unroll
  for (int ni = 0; ni < 14; ++ni) {
    if (ni < nv) {
      const int n = by * 224 + ni * 16 + frow;
      const float bvl = b_v[n];
      #pragma unroll
      for (int r = 0; r < 4; ++r) {
        const int m = bm + wave * 16 + orow + r;
        v[(size_t)m * CDIM + n] = (__bf16)(acc[ni][r] + bvl);
      }
    }
  }

  if (by == 1) {
    __syncthreads();   // all waves done with Bs before Ls overlay
    float bvl[4];
    #pragma unroll
    for (int ni = 0; ni < 4; ++ni) bvl[ni] = bpad[ni * 16 + frow];
    #pragma unroll
    for (int ni = 0; ni < 4; ++ni)
      #pragma unroll
      for (int r = 0; r < 4; ++r)
        Ls[wave * 16 + orow + r][ni * 16 + frow] = acc[10 + ni][r] + bvl[ni];
    __syncthreads();

    #pragma unroll
    for (int it = 0; it < 2; ++it) {
      const int task = it * 256 + tid;
      if (task < 64 * HEADS) {
        const int pl = task / HEADS;
        const int h  = task % HEADS;
        const float* row = &Ls[pl][h * 9];
        float m = row[0];
        #pragma unroll
        for (int w = 1; w < 9; ++w) m = fmaxf(m, row[w]);
        float e[9], s = 0.f;
        #pragma unroll
        for (int w = 0; w < 9; ++w) { e[w] = __expf(row[w] - m); s += e[w]; }
        const float inv = 1.f / s;
        float* op = &attn[(size_t)(bm + pl) * NLOGIT + h * 9];
        #pragma unroll
        for (int w = 0; w < 9; ++w) op[w] = e[w] * inv;
      }
    }
  }
}

// ---------------------------------------------------------------------------
// Proj GEMM, split-N, same T4 pipeline. Per-iter per-wave vmem:
// 1 A-load + 3 glds16 -> vmcnt(4) steady. Out fp32.
// ---------------------------------------------------------------------------
__global__ __launch_bounds__(256) void gemm_proj_kernel(
    const __bf16* __restrict__ Y, const __bf16* __restrict__ Wtp_frag,
    const float* __restrict__ bias, float* __restrict__ Out) {
  __shared__ __bf16 Bs[3 * 12 * 512];   // 36864B, 3 bufs

  const int tid  = threadIdx.x;
  const int wave = tid >> 6;
  const int lane = tid & 63;
  const int bm   = blockIdx.x * 64;
  const int by   = blockIdx.y;
  const int nbase = by * 12;
  const int frow = lane & 15;
  const int fk8  = (lane >> 4) * 8;

  const int arow = bm + wave * 16 + frow;
  const __bf16* yrow = Y + (size_t)arow * CDIM + fk8;

  f32x4 acc[12] = {};
  bf16x8 pa[2];

  pa[0] = *(const bf16x8*)(yrow + 0);
  #pragma unroll
  for (int c = 0; c < 3; ++c) {
    const int chunk = wave * 3 + c;
    glds16(Wtp_frag + ((size_t)(nbase + chunk) * 64 + lane) * 8,
           Bs + chunk * 512);
  }
  pa[1] = *(const bf16x8*)(yrow + 32);
  #pragma unroll
  for (int c = 0; c < 3; ++c) {
    const int chunk = wave * 3 + c;
    glds16(Wtp_frag + ((size_t)(NCH_P + nbase + chunk) * 64 + lane) * 8,
           Bs + 12 * 512 + chunk * 512);
  }

  #pragma unroll
  for (int ks = 0; ks < KSTEPS; ++ks) {
    if (ks < KSTEPS - 1) {
      asm volatile("s_waitcnt vmcnt(4)" ::: "memory");
    } else {
      asm volatile("s_waitcnt vmcnt(0)" ::: "memory");
    }
    __builtin_amdgcn_s_barrier();

    const bf16x8 a = pa[ks & 1];

    if (ks + 2 < KSTEPS) {
      pa[ks & 1] = *(const bf16x8*)(yrow + (ks + 2) * 32);
      __bf16* dst = Bs + ((ks + 2) % 3) * 12 * 512;
      #pragma unroll
      for (int c = 0; c < 3; ++c) {
        const int chunk = wave * 3 + c;
        glds16(Wtp_frag +
                   ((size_t)((ks + 2) * NCH_P + nbase + chunk) * 64 + lane) * 8,
               dst + chunk * 512);
      }
    }

    const __bf16* Bc = Bs + (ks % 3) * 12 * 512;
    #pragma unroll
    for (int ni = 0; ni < 12; ++ni) {
      const bf16x8 b = *(const bf16x8*)&Bc[(ni * 64 + lane) * 8];
      acc[ni] = __builtin_amdgcn_mfma_f32_16x16x32_bf16(a, b, acc[ni], 0, 0, 0);
    }
  }

  const int orow = (lane >> 4) * 4;
  #pragma unroll
  for (int ni = 0; ni < 12; ++ni) {
    const int n = by * 192 + ni * 16 + frow;
    const float bvl = bias[n];
    #pragma unroll
    for (int r = 0; r < 4; ++r) {
      const int m = bm + wave * 16 + orow + r;
      Out[(size_t)m * CDIM + n] = acc[ni][r] + bvl;
    }
  }
}

// ---------------------------------------------------------------------------
// Window aggregation, 4 vertically-adjacent pixels per thread (unchanged).
// ---------------------------------------------------------------------------
__global__ __launch_bounds__(256) void aggregate_kernel(
    const __bf16* __restrict__ v, const float* __restrict__ attn,
    __bf16* __restrict__ y) {
  const int idx = blockIdx.x * 256 + threadIdx.x;  // NPIX/4 * 48 = 602112
  const int cg = idx % 48;
  const int pg = idx / 48;
  const int c  = cg * 8;
  const int b  = pg / ((HH / 4) * WW);
  const int r2 = pg % ((HH / 4) * WW);
  const int i0 = (r2 / WW) * 4;
  const int j  = r2 % WW;
  const int head = c >> 6;

  const int pbase = (b * HH + i0) * WW + j;
  float aw[4][9];
  #pragma unroll
  for (int p = 0; p < 4; ++p) {
    const float* ap = attn + (size_t)(pbase + p * WW) * NLOGIT + head * 9;
    #pragma unroll
    for (int w = 0; w < 9; ++w) aw[p][w] = ap[w];
  }

  const bool j0ok = (j > 0), j2ok = (j < WW - 1);
  float acc[4][8] = {};

  #pragma unroll
  for (int li = 0; li < 6; ++li) {
    const int ii = i0 - 1 + li;
    if (ii < 0 || ii >= HH) continue;
    const __bf16* vrow = v + ((size_t)(b * HH + ii) * WW + j) * CDIM + c;
    float ch[3][8];
    #pragma unroll
    for (int kj = 0; kj < 3; ++kj) {
      const bool ok = (kj == 0) ? j0ok : (kj == 2) ? j2ok : true;
      if (ok) {
        const bf16x8 vv = *(const bf16x8*)(vrow + (kj - 1) * CDIM);
        #pragma unroll
        for (int q = 0; q < 8; ++q) ch[kj][q] = (float)vv[q];
      } else {
        #pragma unroll
        for (int q = 0; q < 8; ++q) ch[kj][q] = 0.f;
      }
    }
    #pragma unroll
    for (int p = 0; p < 4; ++p) {
      const int ki = li - p;
      if (ki < 0 || ki > 2) continue;
      #pragma unroll
      for (int kj = 0; kj < 3; ++kj) {
        const float w = aw[p][ki * 3 + kj];
        #pragma unroll
        for (int q = 0; q < 8; ++q) acc[p][q] += w * ch[kj][q];
      }
    }
  }

  #pragma unroll
  for (int p = 0; p < 4; ++p) {
    bf16x8 o;
    #pragma unroll
    for (int q = 0; q < 8; ++q) o[q] = (__bf16)acc[p][q];
    *(bf16x8*)&y[(size_t)(pbase + p * WW) * CDIM + c] = o;
  }
}

// ---------------------------------------------------------------------------
extern "C" void kernel_launch(void* const* d_in, const int* in_sizes, int n_in,
                              void* d_out, int out_size, void* d_ws,
                              size_t ws_size, hipStream_t stream) {
  const float* x      = (const float*)d_in[0];
  const float* W_attn = (const float*)d_in[1];
  const float* b_attn = (const float*)d_in[2];
  const float* W_v    = (const float*)d_in[3];
  const float* b_v    = (const float*)d_in[4];
  const float* W_proj = (const float*)d_in[5];
  const float* b_proj = (const float*)d_in[6];
  float* out = (float*)d_out;

  char* w = (char*)d_ws;
  __bf16* v    = (__bf16*)w;  w += (size_t)NPIX * CDIM * 2;   // 38.5MB
  __bf16* y    = (__bf16*)w;  w += (size_t)NPIX * CDIM * 2;   // 38.5MB
  float*  attn = (float*)w;   w += (size_t)NPIX * NLOGIT * 4; // 10.8MB
  __bf16* Wcat_frag = (__bf16*)w;  w += (size_t)NCAT * CDIM * 2;  // 344KB
  __bf16* Wtp_frag  = (__bf16*)w;  w += (size_t)CDIM * CDIM * 2;  // 288KB
  float*  bpad = (float*)w;   w += 64 * 4;

  // prep (one dispatch): fragment-major weights
  const int prep_n = KSTEPS * NCH_V * 64 + KSTEPS * NCH_P * 64 + 64;
  prep_kernel<<<(prep_n + 255) / 256, 256, 0, stream>>>(
      W_v, W_proj, W_attn, b_attn, Wcat_frag, Wtp_frag, bpad);

  // 1. merged split-N: v-GEMM + logits/softmax (T4 pipeline)
  gemm_v_logit_kernel<<<dim3(NPIX / 64, 2), 256, 0, stream>>>(
      x, Wcat_frag, b_v, v, bpad, attn);

  // 2. window aggregation -> y (bf16), 4 px/thread
  aggregate_kernel<<<(NPIX / 4 * 48) / 256, 256, 0, stream>>>(v, attn, y);

  // 3. out = y @ Wtp^T + b_proj (fp32 out), T4 pipeline
  gemm_proj_kernel<<<dim3(NPIX / 64, 2), 256, 0, stream>>>(
      y, Wtp_frag, b_proj, out);
}